// Round 4
// baseline (570.103 us; speedup 1.0000x reference)
//
#include <hip/hip_runtime.h>
#include <hip/hip_bf16.h>

// ---------------- problem constants ----------------
#define BB    128
#define TT    65536
#define LF    32
#define HOP   16
#define DELTA 3
#define HID   32
#define GRUH  64
#define SWIN  96          // DELTA*HOP*2
#define SHOP  48          // DELTA*HOP
#define NF    4095        // (TT-LF)/HOP + 1
#define NS    1364        // (TT-SWIN)/SHOP + 1

// ---- chunked-scan parameters ----
// K2O=32 (r2-proven): ~2e-10 attenuation of unknown init state; absmax
// unchanged vs K2O=48. 96 serial steps/wave.
#define K2C    64
#define K2O    32
#define NCHUNK ((NS + K2C - 1) / K2C)   // 22

// ---------------- ws layout (float indices), total 178.8 MB (proven safe) ----
#define GI_BASE   0ull
#define HS_BASE   (GI_BASE + (unsigned long long)BB*NS*192)

typedef float v2f __attribute__((ext_vector_type(2)));

__device__ __forceinline__ float sigmoidf_(float x) {
    return __builtin_amdgcn_rcpf(1.f + __builtin_amdgcn_exp2f(-1.44269504f * x));
}
__device__ __forceinline__ float tanhf_(float x) {
    return 1.f - 2.f * __builtin_amdgcn_rcpf(1.f + __builtin_amdgcn_exp2f(2.88539008f * x));
}
__device__ __forceinline__ v2f pkfma(v2f a, v2f b, v2f c) {
    return __builtin_elementwise_fma(a, b, c);
}

// ---------------- K1: gi[b][n][j] = b_ih[j] + slow_frame(b,n) . w_ih[j,:] ----
// r3 falsified the weight-streaming theory (VGPR=32, perf ~unchanged vs r0).
// Real constraint: x s_load latency chain (17 serial segs/item) with only
// ~4.4 waves/SIMD to overlap (6-wave blocks at 55% occupancy). Fix: 1-WAVE
// BLOCKS. Rows split into 6 groups of 32; block = 64 thr = (rloc, half);
// rg = blockIdx.x % 6 is block-constant (stride 8256 = 6*1376). 1-wave
// blocks at VGPR<=~64 reach 6-8 waves/SIMD -> ~2x MLP; the 6 rg-sharers of
// each x segment are dispatch-adjacent -> L2/L3 hits for 5 of 6.
// Writes: 32 floats @ rg*32 offset = one aligned 128B line per store.
#define K1G    16
#define K1NG   ((NS + K1G - 1) / K1G)   // 86 groups
#define K1RG   6                        // row-groups of 32 rows
#define K1NBLK 8256                     // = 6 * 1376; 8 items per block exactly
__global__ __launch_bounds__(64, 6) void k1_gi(const float* __restrict__ x,
                                               const float* __restrict__ wih,
                                               const float* __restrict__ bih,
                                               float* __restrict__ gi) {
    int lane  = threadIdx.x;
    int half  = lane & 1;               // 0: frame cols 0..47, 1: cols 48..95
    int rloc  = lane >> 1;              // 0..31
    int rg    = blockIdx.x % K1RG;      // constant across grid-stride walk
    int row   = rg * 32 + rloc;         // 0..191

    v2f w[24];
    const v2f* wr = (const v2f*)(wih + (size_t)row * 96 + half * 48);
#pragma unroll
    for (int k = 0; k < 24; ++k) w[k] = wr[k];
    float bias = bih[row];

    const int nwi = K1NG * BB * K1RG;   // 66048 work items
#pragma unroll 1
    for (int wi = blockIdx.x; wi < nwi; wi += K1NBLK) {
        int pos = wi / K1RG;            // 0..11007
        int b   = pos & (BB - 1);
        int n0  = (pos >> 7) * K1G;
        const float4* xb = (const float4*)(x + (size_t)b * TT);
        float* gout = gi + ((size_t)b * NS + n0) * 192 + row;

        float prev = 0.f;               // this half's partial for frame n0+s-1
#pragma unroll 1
        for (int s = 0; s <= K1G; ++s) {
            int seg = n0 + s; if (seg > NS) seg = NS;    // clamp: loads in-bounds
            const float4* xp = xb + (size_t)seg * 12;
            float4 xs[12];
#pragma unroll
            for (int k = 0; k < 12; ++k) xs[k] = xp[k];

            v2f a0 = {0.f,0.f}, a1 = {0.f,0.f};
#pragma unroll
            for (int k = 0; k < 12; ++k) {
                v2f p0; p0.x = xs[k].x; p0.y = xs[k].y;
                v2f p1; p1.x = xs[k].z; p1.y = xs[k].w;
                a0 = pkfma(w[2*k],   p0, a0);
                a1 = pkfma(w[2*k+1], p1, a1);
            }
            float cur = a0.x + a0.y + a1.x + a1.y;

            if (s > 0) {
                // frame f = n0+s-1: half0 contributed at iter s-1, half1 now.
                float mine  = half ? cur : prev;
                float other = __shfl_xor(mine, 1, 64);
                int f = n0 + s - 1;
                if (half == 0 && f < NS)
                    gout[(size_t)(s - 1) * 192] = mine + other + bias;
            }
            prev = cur;
        }
    }
}

// ---------------- K2: chunked GRU scan (r0-proven structure, K2O=32) --------
// blockIdx.x = chunk, blockIdx.y = batch; 1 wave each. Lane j owns W_hh rows
// {j,64+j,128+j} in regs; h broadcast via tiny LDS (single wave, no barriers);
// 2-deep gi prefetch; store-in-loop (measured fastest structure).
__global__ __launch_bounds__(64) void k2_scan(const float* __restrict__ whh,
                                              const float* __restrict__ bhh,
                                              const float* __restrict__ gi,
                                              float* __restrict__ hs) {
    int c = blockIdx.x;
    int b = blockIdx.y;
    int j = threadIdx.x;
    __shared__ __align__(16) float hsh[GRUH];

    int eStart = c * K2C;
    int eEnd   = eStart + K2C; if (eEnd > NS) eEnd = NS;
    int t0     = eStart - K2O; if (t0 < 0) t0 = 0;

    v2f wr[32], wz[32], wn[32];
    const v2f* rr = (const v2f*)(whh + (size_t)j * 64);
    const v2f* rz = (const v2f*)(whh + (size_t)(64 + j) * 64);
    const v2f* rn = (const v2f*)(whh + (size_t)(128 + j) * 64);
#pragma unroll
    for (int k = 0; k < 32; ++k) { wr[k] = rr[k]; wz[k] = rz[k]; wn[k] = rn[k]; }
    float br = bhh[j], bz = bhh[64 + j], bn = bhh[128 + j];

    hsh[j] = 0.f;
    float hj = 0.f;
    const float* gp = gi + (size_t)b * NS * 192;
    float* hp = hs + (size_t)b * NS * 64 + j;

    // 2-deep shift prefetch
    const float* q0 = gp + (size_t)t0 * 192;
    const float* q1 = gp + (size_t)(t0 + 1) * 192;
    float g0r = q0[j], g0z = q0[64 + j], g0n = q0[128 + j];
    float g1r = q1[j], g1z = q1[64 + j], g1n = q1[128 + j];

#pragma unroll 1
    for (int t = t0; t < eEnd; ++t) {
        const float* gq = gp + (size_t)(t + 2) * 192;   // benign over-read (lands in hs)
        float g2r = gq[j], g2z = gq[64 + j], g2n = gq[128 + j];

        v2f ar0 = {0.f,0.f}, ar1 = {0.f,0.f};
        v2f az0 = {0.f,0.f}, az1 = {0.f,0.f};
        v2f an0 = {0.f,0.f}, an1 = {0.f,0.f};
        const float4* h4 = (const float4*)hsh;
#pragma unroll
        for (int k4 = 0; k4 < 16; ++k4) {
            float4 hv = h4[k4];
            v2f p0; p0.x = hv.x; p0.y = hv.y;
            v2f p1; p1.x = hv.z; p1.y = hv.w;
            ar0 = pkfma(wr[2*k4],   p0, ar0);
            ar1 = pkfma(wr[2*k4+1], p1, ar1);
            az0 = pkfma(wz[2*k4],   p0, az0);
            az1 = pkfma(wz[2*k4+1], p1, az1);
            an0 = pkfma(wn[2*k4],   p0, an0);
            an1 = pkfma(wn[2*k4+1], p1, an1);
        }
        float sr = ar0.x + ar0.y + ar1.x + ar1.y + br;
        float sz = az0.x + az0.y + az1.x + az1.y + bz;
        float sn = an0.x + an0.y + an1.x + an1.y + bn;
        float r  = sigmoidf_(g0r + sr);
        float z  = sigmoidf_(g0z + sz);
        float nn = tanhf_(fmaf(r, sn, g0n));
        hj = fmaf(z, hj - nn, nn);           // (1-z)*n + z*h
        hsh[j] = hj;                         // single wave: program-order vs reads

        if (t >= eStart) hp[(size_t)t * 64] = hj;   // emit range only

        g0r = g1r; g0z = g1z; g0n = g1n;
        g1r = g2r; g1z = g2z; g1n = g2n;
    }
}

// ---------------- K3: fused out-proj + fast path --------------------------
// Phase P: eps rows computed with outw row held in 64 VGPRs per lane (loaded
// once per block from global, L1-resident) instead of per-(si,o) 128B LDS
// reads -- phase P's LDS-pipe traffic drops ~4x; hrow reads are wave-uniform
// broadcasts (cheap). Accumulation order identical to previous version.
// Phase F: fc1 -> FiLM -> relu -> fc2 -> overlap-add (unchanged).
#define SROWS 24
__global__ __launch_bounds__(256) void k3_fast(const float* __restrict__ x,
                                               const float* __restrict__ fc1w,
                                               const float* __restrict__ fc1b,
                                               const float* __restrict__ fc2w,
                                               const float* __restrict__ fc2b,
                                               const float* __restrict__ outw,
                                               const float* __restrict__ outb,
                                               const float* __restrict__ hs,
                                               float* __restrict__ out) {
    int b  = blockIdx.y;
    int m0 = blockIdx.x * 64;
    int tid = threadIdx.x;

    __shared__ __align__(16) float gbs[SROWS * 64];   // 1536 floats (persistent)
    __shared__ __align__(16) float scr[5696];         // union scratch (22.8 KB)

    int fbase = m0 - 1;
    int s0 = (m0 - 1) / 3 - 1; if (s0 < 0) s0 = 0;

    // ---- phase P: eps rows [s0, s0+SROWS) ----
    {
        float* hsl = scr;              // [SROWS][64]
        const float* hsb = hs + (size_t)b * NS * 64;
        int o = tid & 63, q = tid >> 6;       // q = wave id (uniform per wave)

        // outw row o -> regs (16 KB/block from global; L1-cached across blocks)
        v2f wo[32];
        const v2f* wop = (const v2f*)(outw + (size_t)o * 64);
#pragma unroll
        for (int k = 0; k < 32; ++k) wo[k] = wop[k];
        float bias = outb[o];

        for (int i = tid; i < SROWS * 64; i += 256) {
            int si = i >> 6, k = i & 63;
            int t = s0 + si;
            hsl[i] = (t < NS) ? hsb[(size_t)t * 64 + k] : 0.f;
        }
        __syncthreads();

        for (int si = q; si < SROWS; si += 4) {
            const float* hrow = hsl + si * 64;     // wave-uniform -> broadcast
            v2f a0 = {0.f,0.f}, a1 = {0.f,0.f};
#pragma unroll
            for (int k = 0; k < 16; ++k) {
                v2f p0; p0.x = hrow[4*k];   p0.y = hrow[4*k+1];
                v2f p1; p1.x = hrow[4*k+2]; p1.y = hrow[4*k+3];
                a0 = pkfma(wo[2*k],   p0, a0);
                a1 = pkfma(wo[2*k+1], p1, a1);
            }
            gbs[si * 64 + o] = a0.x + a0.y + a1.x + a1.y + bias;
        }
        __syncthreads();   // gbs done; scr free for reuse
    }

    // ---- phase F ----
    float* xs  = scr;                  // 1056
    float* h1s = scr + 1056;           // 2080
    float* ys  = scr + 3136;           // 2080

    long xstart = (long)fbase * HOP;
    const float* xb = x + (size_t)b * TT;
    for (int i = tid; i < 1056; i += 256) {
        long p = xstart + i;
        xs[i] = (p >= 0 && p < TT) ? xb[p] : 0.f;
    }

    int j  = tid & 31;
    int fi = tid >> 5;
    v2f w1[16], w2[16];
    {
        const v2f* r1 = (const v2f*)(fc1w + (size_t)j * 32);
        const v2f* r2 = (const v2f*)(fc2w + (size_t)j * 32);
#pragma unroll
        for (int k = 0; k < 16; ++k) { w1[k] = r1[k]; w2[k] = r2[k]; }
    }
    float b1 = fc1b[j];
    float b2 = fc2b[j];
    __syncthreads();

    // phase A: h1 = relu(g*fc1 + b)
    for (int ff = fi; ff < 65; ff += 8) {
        int f = fbase + ff;
        float v = 0.f;
        if (f >= 0 && f < NF) {
            const float4* xf4 = (const float4*)(xs + ff * HOP);
            v2f a0 = {0.f,0.f}, a1 = {0.f,0.f};
#pragma unroll
            for (int k4 = 0; k4 < 8; ++k4) {
                float4 xv = xf4[k4];
                v2f p0; p0.x = xv.x; p0.y = xv.y;
                v2f p1; p1.x = xv.z; p1.y = xv.w;
                a0 = pkfma(w1[2*k4],   p0, a0);
                a1 = pkfma(w1[2*k4+1], p1, a1);
            }
            float acc = a0.x + a0.y + a1.x + a1.y + b1;
            int sidx = f / DELTA - 1; if (sidx < 0) sidx = 0;
            const float* gp = gbs + (sidx - s0) * 64;
            v = fmaxf(fmaf(gp[j], acc, gp[32 + j]), 0.f);
        }
        h1s[ff * 32 + j] = v;
    }
    __syncthreads();

    // phase B: y = h1 @ fc2^T + fc2_b
    for (int ff = fi; ff < 65; ff += 8) {
        int f = fbase + ff;
        float v = 0.f;
        if (f >= 0 && f < NF) {
            const float4* hf4 = (const float4*)(h1s + ff * 32);
            v2f a0 = {0.f,0.f}, a1 = {0.f,0.f};
#pragma unroll
            for (int k4 = 0; k4 < 8; ++k4) {
                float4 hv = hf4[k4];
                v2f p0; p0.x = hv.x; p0.y = hv.y;
                v2f p1; p1.x = hv.z; p1.y = hv.w;
                a0 = pkfma(w2[2*k4],   p0, a0);
                a1 = pkfma(w2[2*k4+1], p1, a1);
            }
            v = a0.x + a0.y + a1.x + a1.y + b2;
        }
        ys[ff * 32 + j] = v;
    }
    __syncthreads();

    // phase C: overlap-add -> out (fp32)
    float* ob = out + (size_t)b * TT + (size_t)m0 * HOP;
    for (int i = tid; i < 64 * 16; i += 256) {
        int ml = i >> 4, ii = i & 15;
        ob[i] = ys[(ml + 1) * 32 + ii] + ys[ml * 32 + 16 + ii];
    }
}

// ---------------- launcher ----------------
extern "C" void kernel_launch(void* const* d_in, const int* in_sizes, int n_in,
                              void* d_out, int out_size, void* d_ws, size_t ws_size,
                              hipStream_t stream) {
    const float* x     = (const float*)d_in[0];
    const float* fc1w  = (const float*)d_in[1];
    const float* fc1b  = (const float*)d_in[2];
    const float* fc2w  = (const float*)d_in[3];
    const float* fc2b  = (const float*)d_in[4];
    const float* wih   = (const float*)d_in[5];
    const float* whh   = (const float*)d_in[6];
    const float* bih   = (const float*)d_in[7];
    const float* bhh   = (const float*)d_in[8];
    const float* outw  = (const float*)d_in[9];
    const float* outb  = (const float*)d_in[10];

    float* ws  = (float*)d_ws;
    float* gi  = ws + GI_BASE;
    float* hs  = ws + HS_BASE;
    float* out = (float*)d_out;

    k1_gi<<<K1NBLK, 64, 0, stream>>>(x, wih, bih, gi);

    k2_scan<<<dim3(NCHUNK, BB), 64, 0, stream>>>(whh, bhh, gi, hs);

    k3_fast<<<dim3((NF + 1) / 64, BB), 256, 0, stream>>>(x, fc1w, fc1b, fc2w, fc2b,
                                                         outw, outb, hs, out);
}

// Round 5
// 519.657 us; speedup vs baseline: 1.0971x; 1.0971x over previous
//
#include <hip/hip_runtime.h>
#include <hip/hip_bf16.h>

// ---------------- problem constants ----------------
#define BB    128
#define TT    65536
#define LF    32
#define HOP   16
#define DELTA 3
#define HID   32
#define GRUH  64
#define SWIN  96          // DELTA*HOP*2
#define SHOP  48          // DELTA*HOP
#define NF    4095        // (TT-LF)/HOP + 1
#define NS    1364        // (TT-SWIN)/SHOP + 1

// ---- chunked-scan parameters ----
// K2O=32 (r2-proven): ~2e-10 attenuation of unknown init state.
// K2C=43: 32 chunks x 128 b = 4096 waves = the VGPR-116 residency cap
// (16 waves/CU); serial wall 75 steps (vs 96 at K2C=64). r2 proved wall
// scales with step count at constant 1.48us/step.
#define K2C    43
#define K2O    32
#define NCHUNK ((NS + K2C - 1) / K2C)   // 32

// ---------------- ws layout (float indices), total 178.8 MB (proven safe) ----
#define GI_BASE   0ull
#define HS_BASE   (GI_BASE + (unsigned long long)BB*NS*192)

typedef float v2f __attribute__((ext_vector_type(2)));

__device__ __forceinline__ float sigmoidf_(float x) {
    return __builtin_amdgcn_rcpf(1.f + __builtin_amdgcn_exp2f(-1.44269504f * x));
}
__device__ __forceinline__ float tanhf_(float x) {
    return 1.f - 2.f * __builtin_amdgcn_rcpf(1.f + __builtin_amdgcn_exp2f(2.88539008f * x));
}
__device__ __forceinline__ v2f pkfma(v2f a, v2f b, v2f c) {
    return __builtin_elementwise_fma(a, b, c);
}

// ---------------- K1: gi[b][n][j] = b_ih[j] + slow_frame(b,n) . w_ih[j,:] ----
// r4 post-mortem: 1-wave blocks gave 67% occupancy (good) but FETCH went
// exactly 6x (202MB) -- the 6 row-group sharers of each x segment landed on
// DIFFERENT XCDs (round-robin dispatch, private L2s) and each missed to HBM.
// Fix: XCD-aware swizzle. Physical block p: xcd=p&7, q=p>>3, rg=q%6, u=q/6;
// item k: pos = xcd*1376 + u + 172*k. Under xcd=blockIdx%8 round-robin all
// 6 rg-sharers of a pos run on the SAME XCD -> 5/6 x-reads hit that XCD's L2.
// Working set/XCD ~1.5MB < 4MB L2. Writes: 32 floats @ rg*32 = one aligned
// 128B line per store (unchanged).
#define K1G    16
#define K1NG   ((NS + K1G - 1) / K1G)   // 86 groups
#define K1RG   6                        // row-groups of 32 rows
#define K1NBLK 8256                     // = 8 xcd * 6 rg * 172 u
__global__ __launch_bounds__(64, 6) void k1_gi(const float* __restrict__ x,
                                               const float* __restrict__ wih,
                                               const float* __restrict__ bih,
                                               float* __restrict__ gi) {
    int lane  = threadIdx.x;
    int half  = lane & 1;               // 0: frame cols 0..47, 1: cols 48..95
    int rloc  = lane >> 1;              // 0..31
    int p     = blockIdx.x;
    int xcd   = p & 7;                  // assumed dispatch XCD (perf-only)
    int q     = p >> 3;                 // 0..1031
    int rg    = q % K1RG;               // row-group, block-constant
    int u     = q / K1RG;               // 0..171
    int row   = rg * 32 + rloc;         // 0..191

    v2f w[24];
    const v2f* wr = (const v2f*)(wih + (size_t)row * 96 + half * 48);
#pragma unroll
    for (int k = 0; k < 24; ++k) w[k] = wr[k];
    float bias = bih[row];

#pragma unroll 1
    for (int it = 0; it < 8; ++it) {
        int pos = xcd * 1376 + u + 172 * it;   // 0..11007, bijective over grid
        int b   = pos & (BB - 1);
        int n0  = (pos >> 7) * K1G;
        const float4* xb = (const float4*)(x + (size_t)b * TT);
        float* gout = gi + ((size_t)b * NS + n0) * 192 + row;

        float prev = 0.f;               // this half's partial for frame n0+s-1
#pragma unroll 1
        for (int s = 0; s <= K1G; ++s) {
            int seg = n0 + s; if (seg > NS) seg = NS;    // clamp: loads in-bounds
            const float4* xp = xb + (size_t)seg * 12;
            float4 xs[12];
#pragma unroll
            for (int k = 0; k < 12; ++k) xs[k] = xp[k];

            v2f a0 = {0.f,0.f}, a1 = {0.f,0.f};
#pragma unroll
            for (int k = 0; k < 12; ++k) {
                v2f p0; p0.x = xs[k].x; p0.y = xs[k].y;
                v2f p1; p1.x = xs[k].z; p1.y = xs[k].w;
                a0 = pkfma(w[2*k],   p0, a0);
                a1 = pkfma(w[2*k+1], p1, a1);
            }
            float cur = a0.x + a0.y + a1.x + a1.y;

            if (s > 0) {
                // frame f = n0+s-1: half0 contributed at iter s-1, half1 now.
                float mine  = half ? cur : prev;
                float other = __shfl_xor(mine, 1, 64);
                int f = n0 + s - 1;
                if (half == 0 && f < NS)
                    gout[(size_t)(s - 1) * 192] = mine + other + bias;
            }
            prev = cur;
        }
    }
}

// ---------------- K2: chunked GRU scan (r0-proven structure, K2C=43) --------
// blockIdx.x = chunk, blockIdx.y = batch; 1 wave each. Lane j owns W_hh rows
// {j,64+j,128+j} in regs; h broadcast via tiny LDS (single wave, no barriers);
// 2-deep gi prefetch; store-in-loop (measured fastest structure).
__global__ __launch_bounds__(64) void k2_scan(const float* __restrict__ whh,
                                              const float* __restrict__ bhh,
                                              const float* __restrict__ gi,
                                              float* __restrict__ hs) {
    int c = blockIdx.x;
    int b = blockIdx.y;
    int j = threadIdx.x;
    __shared__ __align__(16) float hsh[GRUH];

    int eStart = c * K2C;
    int eEnd   = eStart + K2C; if (eEnd > NS) eEnd = NS;
    int t0     = eStart - K2O; if (t0 < 0) t0 = 0;

    v2f wr[32], wz[32], wn[32];
    const v2f* rr = (const v2f*)(whh + (size_t)j * 64);
    const v2f* rz = (const v2f*)(whh + (size_t)(64 + j) * 64);
    const v2f* rn = (const v2f*)(whh + (size_t)(128 + j) * 64);
#pragma unroll
    for (int k = 0; k < 32; ++k) { wr[k] = rr[k]; wz[k] = rz[k]; wn[k] = rn[k]; }
    float br = bhh[j], bz = bhh[64 + j], bn = bhh[128 + j];

    hsh[j] = 0.f;
    float hj = 0.f;
    const float* gp = gi + (size_t)b * NS * 192;
    float* hp = hs + (size_t)b * NS * 64 + j;

    // 2-deep shift prefetch
    const float* q0 = gp + (size_t)t0 * 192;
    const float* q1 = gp + (size_t)(t0 + 1) * 192;
    float g0r = q0[j], g0z = q0[64 + j], g0n = q0[128 + j];
    float g1r = q1[j], g1z = q1[64 + j], g1n = q1[128 + j];

#pragma unroll 1
    for (int t = t0; t < eEnd; ++t) {
        const float* gq = gp + (size_t)(t + 2) * 192;   // benign over-read (lands in hs)
        float g2r = gq[j], g2z = gq[64 + j], g2n = gq[128 + j];

        v2f ar0 = {0.f,0.f}, ar1 = {0.f,0.f};
        v2f az0 = {0.f,0.f}, az1 = {0.f,0.f};
        v2f an0 = {0.f,0.f}, an1 = {0.f,0.f};
        const float4* h4 = (const float4*)hsh;
#pragma unroll
        for (int k4 = 0; k4 < 16; ++k4) {
            float4 hv = h4[k4];
            v2f p0; p0.x = hv.x; p0.y = hv.y;
            v2f p1; p1.x = hv.z; p1.y = hv.w;
            ar0 = pkfma(wr[2*k4],   p0, ar0);
            ar1 = pkfma(wr[2*k4+1], p1, ar1);
            az0 = pkfma(wz[2*k4],   p0, az0);
            az1 = pkfma(wz[2*k4+1], p1, az1);
            an0 = pkfma(wn[2*k4],   p0, an0);
            an1 = pkfma(wn[2*k4+1], p1, an1);
        }
        float sr = ar0.x + ar0.y + ar1.x + ar1.y + br;
        float sz = az0.x + az0.y + az1.x + az1.y + bz;
        float sn = an0.x + an0.y + an1.x + an1.y + bn;
        float r  = sigmoidf_(g0r + sr);
        float z  = sigmoidf_(g0z + sz);
        float nn = tanhf_(fmaf(r, sn, g0n));
        hj = fmaf(z, hj - nn, nn);           // (1-z)*n + z*h
        hsh[j] = hj;                         // single wave: program-order vs reads

        if (t >= eStart) hp[(size_t)t * 64] = hj;   // emit range only

        g0r = g1r; g0z = g1z; g0n = g1n;
        g1r = g2r; g1z = g2z; g1n = g2n;
    }
}

// ---------------- K3: fused out-proj + fast path (r3-proven version) -------
// Phase P: compute the <=24 slow-step FiLM rows this block needs directly
// from hs. Phase F: fc1 -> FiLM -> relu -> fc2 -> overlap-add.
// LDS: gbs persistent + scr union (phase P: hsl+outws / phase F: xs+h1s+ys).
#define SROWS 24
__global__ __launch_bounds__(256) void k3_fast(const float* __restrict__ x,
                                               const float* __restrict__ fc1w,
                                               const float* __restrict__ fc1b,
                                               const float* __restrict__ fc2w,
                                               const float* __restrict__ fc2b,
                                               const float* __restrict__ outw,
                                               const float* __restrict__ outb,
                                               const float* __restrict__ hs,
                                               float* __restrict__ out) {
    int b  = blockIdx.y;
    int m0 = blockIdx.x * 64;
    int tid = threadIdx.x;

    __shared__ __align__(16) float gbs[SROWS * 64];   // 1536 floats (persistent)
    __shared__ __align__(16) float scr[5696];         // union scratch (22.8 KB)

    int fbase = m0 - 1;
    int s0 = (m0 - 1) / 3 - 1; if (s0 < 0) s0 = 0;

    // ---- phase P: eps rows [s0, s0+SROWS) ----
    {
        float* hsl   = scr;            // [SROWS][64]
        float* outws = scr + 1536;     // [64][65]  (+1 pad kills 64-stride conflicts)
        const float* hsb = hs + (size_t)b * NS * 64;
        for (int i = tid; i < SROWS * 64; i += 256) {
            int si = i >> 6, k = i & 63;
            int t = s0 + si;
            hsl[i] = (t < NS) ? hsb[(size_t)t * 64 + k] : 0.f;
        }
        for (int i = tid; i < 64 * 64; i += 256) {
            int o = i >> 6, k = i & 63;
            outws[o * 65 + k] = outw[i];
        }
        __syncthreads();
        int o = tid & 63, q = tid >> 6;       // q = wave id (uniform per wave)
        float bias = outb[o];
        for (int si = q; si < SROWS; si += 4) {
            const float* hrow = hsl + si * 64;     // wave-uniform -> broadcast
            const float* wrow = outws + o * 65;    // stride-65 -> conflict-free
            v2f a0 = {0.f,0.f}, a1 = {0.f,0.f};
#pragma unroll
            for (int k = 0; k < 16; ++k) {
                v2f p0; p0.x = hrow[4*k];   p0.y = hrow[4*k+1];
                v2f p1; p1.x = hrow[4*k+2]; p1.y = hrow[4*k+3];
                v2f w0; w0.x = wrow[4*k];   w0.y = wrow[4*k+1];
                v2f w1_; w1_.x = wrow[4*k+2]; w1_.y = wrow[4*k+3];
                a0 = pkfma(w0,  p0, a0);
                a1 = pkfma(w1_, p1, a1);
            }
            gbs[si * 64 + o] = a0.x + a0.y + a1.x + a1.y + bias;
        }
        __syncthreads();   // gbs done; scr free for reuse
    }

    // ---- phase F ----
    float* xs  = scr;                  // 1056
    float* h1s = scr + 1056;           // 2080
    float* ys  = scr + 3136;           // 2080

    long xstart = (long)fbase * HOP;
    const float* xb = x + (size_t)b * TT;
    for (int i = tid; i < 1056; i += 256) {
        long p = xstart + i;
        xs[i] = (p >= 0 && p < TT) ? xb[p] : 0.f;
    }

    int j  = tid & 31;
    int fi = tid >> 5;
    v2f w1[16], w2[16];
    {
        const v2f* r1 = (const v2f*)(fc1w + (size_t)j * 32);
        const v2f* r2 = (const v2f*)(fc2w + (size_t)j * 32);
#pragma unroll
        for (int k = 0; k < 16; ++k) { w1[k] = r1[k]; w2[k] = r2[k]; }
    }
    float b1 = fc1b[j];
    float b2 = fc2b[j];
    __syncthreads();

    // phase A: h1 = relu(g*fc1 + b)
    for (int ff = fi; ff < 65; ff += 8) {
        int f = fbase + ff;
        float v = 0.f;
        if (f >= 0 && f < NF) {
            const float4* xf4 = (const float4*)(xs + ff * HOP);
            v2f a0 = {0.f,0.f}, a1 = {0.f,0.f};
#pragma unroll
            for (int k4 = 0; k4 < 8; ++k4) {
                float4 xv = xf4[k4];
                v2f p0; p0.x = xv.x; p0.y = xv.y;
                v2f p1; p1.x = xv.z; p1.y = xv.w;
                a0 = pkfma(w1[2*k4],   p0, a0);
                a1 = pkfma(w1[2*k4+1], p1, a1);
            }
            float acc = a0.x + a0.y + a1.x + a1.y + b1;
            int sidx = f / DELTA - 1; if (sidx < 0) sidx = 0;
            const float* gp = gbs + (sidx - s0) * 64;
            v = fmaxf(fmaf(gp[j], acc, gp[32 + j]), 0.f);
        }
        h1s[ff * 32 + j] = v;
    }
    __syncthreads();

    // phase B: y = h1 @ fc2^T + fc2_b
    for (int ff = fi; ff < 65; ff += 8) {
        int f = fbase + ff;
        float v = 0.f;
        if (f >= 0 && f < NF) {
            const float4* hf4 = (const float4*)(h1s + ff * 32);
            v2f a0 = {0.f,0.f}, a1 = {0.f,0.f};
#pragma unroll
            for (int k4 = 0; k4 < 8; ++k4) {
                float4 hv = hf4[k4];
                v2f p0; p0.x = hv.x; p0.y = hv.y;
                v2f p1; p1.x = hv.z; p1.y = hv.w;
                a0 = pkfma(w2[2*k4],   p0, a0);
                a1 = pkfma(w2[2*k4+1], p1, a1);
            }
            v = a0.x + a0.y + a1.x + a1.y + b2;
        }
        ys[ff * 32 + j] = v;
    }
    __syncthreads();

    // phase C: overlap-add -> out (fp32)
    float* ob = out + (size_t)b * TT + (size_t)m0 * HOP;
    for (int i = tid; i < 64 * 16; i += 256) {
        int ml = i >> 4, ii = i & 15;
        ob[i] = ys[(ml + 1) * 32 + ii] + ys[ml * 32 + 16 + ii];
    }
}

// ---------------- launcher ----------------
extern "C" void kernel_launch(void* const* d_in, const int* in_sizes, int n_in,
                              void* d_out, int out_size, void* d_ws, size_t ws_size,
                              hipStream_t stream) {
    const float* x     = (const float*)d_in[0];
    const float* fc1w  = (const float*)d_in[1];
    const float* fc1b  = (const float*)d_in[2];
    const float* fc2w  = (const float*)d_in[3];
    const float* fc2b  = (const float*)d_in[4];
    const float* wih   = (const float*)d_in[5];
    const float* whh   = (const float*)d_in[6];
    const float* bih   = (const float*)d_in[7];
    const float* bhh   = (const float*)d_in[8];
    const float* outw  = (const float*)d_in[9];
    const float* outb  = (const float*)d_in[10];

    float* ws  = (float*)d_ws;
    float* gi  = ws + GI_BASE;
    float* hs  = ws + HS_BASE;
    float* out = (float*)d_out;

    k1_gi<<<K1NBLK, 64, 0, stream>>>(x, wih, bih, gi);

    k2_scan<<<dim3(NCHUNK, BB), 64, 0, stream>>>(whh, bhh, gi, hs);

    k3_fast<<<dim3((NF + 1) / 64, BB), 256, 0, stream>>>(x, fc1w, fc1b, fc2w, fc2b,
                                                         outw, outb, hs, out);
}

// Round 6
// 449.206 us; speedup vs baseline: 1.2691x; 1.1568x over previous
//
#include <hip/hip_runtime.h>
#include <hip/hip_bf16.h>

// ---------------- problem constants ----------------
#define BB    128
#define TT    65536
#define LF    32
#define HOP   16
#define DELTA 3
#define HID   32
#define GRUH  64
#define SWIN  96          // DELTA*HOP*2
#define SHOP  48          // DELTA*HOP
#define NF    4095        // (TT-LF)/HOP + 1
#define NS    1364        // (TT-SWIN)/SHOP + 1

// ---- chunked-scan parameters ----
// K2O=32 (r2-proven): ~2e-10 attenuation of unknown init state.
// K2C=43: 32 chunks x 128 b = 4096 waves (residency cap at VGPR<=128);
// serial wall 75 steps. K2C smaller does NOT help: waves beyond the cap
// serialize into a second dispatch round (2x the wall).
#define K2C    43
#define K2O    32
#define NCHUNK ((NS + K2C - 1) / K2C)   // 32

// ---------------- ws layout (float indices), total 178.8 MB (proven safe) ----
#define GI_BASE   0ull
#define HS_BASE   (GI_BASE + (unsigned long long)BB*NS*192)

typedef float v2f __attribute__((ext_vector_type(2)));

__device__ __forceinline__ float sigmoidf_(float x) {
    return __builtin_amdgcn_rcpf(1.f + __builtin_amdgcn_exp2f(-1.44269504f * x));
}
__device__ __forceinline__ float tanhf_(float x) {
    return 1.f - 2.f * __builtin_amdgcn_rcpf(1.f + __builtin_amdgcn_exp2f(2.88539008f * x));
}
__device__ __forceinline__ v2f pkfma(v2f a, v2f b, v2f c) {
    return __builtin_elementwise_fma(a, b, c);
}

// ---------------- K1: gi[b][n][j] = b_ih[j] + slow_frame(b,n) . w_ih[j,:] ----
// r3-proven structure (157us), restored after r4/r5 falsified the 1-wave-block
// path (r5: FETCH fixed by XCD swizzle but 6x scalar-load chains per segment
// kept dur at 220us; 6-wave blocks amortize one s_load chain across 6 waves).
// Split-K by 2: 384 thr/block, thread=(row,half); each thread holds 24 v2f
// (48 VGPRs) covering cols half*48..+47. Frame n = segments {n,n+1}; half h of
// frame n is a FULL dot of segment n+h; pair combines with one shfl_xor(1).
// 2752 blocks: exactly 4 items each.
#define K1G    16
#define K1NG   ((NS + K1G - 1) / K1G)   // 86 groups
#define K1NBLK 2752
__global__ __launch_bounds__(384, 1) void k1_gi(const float* __restrict__ x,
                                                const float* __restrict__ wih,
                                                const float* __restrict__ bih,
                                                float* __restrict__ gi) {
    int tid  = threadIdx.x;
    int row  = tid >> 1;       // 0..191 = output row
    int half = tid & 1;        // 0: frame cols 0..47, 1: frame cols 48..95

    v2f w[24];
    const v2f* wr = (const v2f*)(wih + (size_t)row * 96 + half * 48);
#pragma unroll
    for (int k = 0; k < 24; ++k) w[k] = wr[k];
    float bias = bih[row];

    const int nwi = K1NG * BB;             // 11008 work items
#pragma unroll 1
    for (int wi = blockIdx.x; wi < nwi; wi += K1NBLK) {
#pragma unroll
        for (int k = 0; k < 24; ++k) asm volatile("" : "+v"(w[k]));  // no remat
        int b  = wi & (BB - 1);
        int n0 = (wi >> 7) * K1G;
        const float4* xb = (const float4*)(x + (size_t)b * TT);
        float* gout = gi + ((size_t)b * NS + n0) * 192 + row;

        float prev = 0.f;                  // half's partial for frame n0+s-1
#pragma unroll 1
        for (int s = 0; s <= K1G; ++s) {
            int seg = n0 + s; if (seg > NS) seg = NS;    // clamp: loads in-bounds
            const float4* xp = xb + (size_t)seg * 12;
            float4 xs[12];
#pragma unroll
            for (int k = 0; k < 12; ++k) xs[k] = xp[k];

            v2f a0 = {0.f,0.f}, a1 = {0.f,0.f};
#pragma unroll
            for (int k = 0; k < 12; ++k) {
                v2f p0; p0.x = xs[k].x; p0.y = xs[k].y;
                v2f p1; p1.x = xs[k].z; p1.y = xs[k].w;
                a0 = pkfma(w[2*k],   p0, a0);
                a1 = pkfma(w[2*k+1], p1, a1);
            }
            float cur = a0.x + a0.y + a1.x + a1.y;

            if (s > 0) {
                // frame f = n0+s-1: half0 contributed at iter s-1, half1 now.
                float mine  = half ? cur : prev;
                float other = __shfl_xor(mine, 1, 64);
                int f = n0 + s - 1;
                if (half == 0 && f < NS)
                    gout[(size_t)(s - 1) * 192] = mine + other + bias;
            }
            prev = cur;
        }
    }
}

// ---------------- K2: chunked GRU scan (K2C=43, 4-deep gi prefetch) ---------
// blockIdx.x = chunk, blockIdx.y = batch; 1 wave each. Lane j owns W_hh rows
// {j,64+j,128+j} in regs; h broadcast via tiny LDS (single wave, no barriers).
// gi prefetch deepened 2->4 (+9 VGPR, stays in the <=128 residency bucket):
// probes whether the ~3560cyc/step residual is gi-load latency. unroll 2 lets
// the compiler rename away the shift movs.
__global__ __launch_bounds__(64) void k2_scan(const float* __restrict__ whh,
                                              const float* __restrict__ bhh,
                                              const float* __restrict__ gi,
                                              float* __restrict__ hs) {
    int c = blockIdx.x;
    int b = blockIdx.y;
    int j = threadIdx.x;
    __shared__ __align__(16) float hsh[GRUH];

    int eStart = c * K2C;
    int eEnd   = eStart + K2C; if (eEnd > NS) eEnd = NS;
    int t0     = eStart - K2O; if (t0 < 0) t0 = 0;

    v2f wr[32], wz[32], wn[32];
    const v2f* rr = (const v2f*)(whh + (size_t)j * 64);
    const v2f* rz = (const v2f*)(whh + (size_t)(64 + j) * 64);
    const v2f* rn = (const v2f*)(whh + (size_t)(128 + j) * 64);
#pragma unroll
    for (int k = 0; k < 32; ++k) { wr[k] = rr[k]; wz[k] = rz[k]; wn[k] = rn[k]; }
    float br = bhh[j], bz = bhh[64 + j], bn = bhh[128 + j];

    hsh[j] = 0.f;
    float hj = 0.f;
    const float* gp = gi + (size_t)b * NS * 192;
    float* hp = hs + (size_t)b * NS * 64 + j;

    // 4-deep shift prefetch (over-reads land in hs region: allocated, benign)
    const float* q0 = gp + (size_t)t0 * 192;
    float g0r = q0[j],           g0z = q0[64 + j],       g0n = q0[128 + j];
    float g1r = q0[192 + j],     g1z = q0[256 + j],      g1n = q0[320 + j];
    float g2r = q0[384 + j],     g2z = q0[448 + j],      g2n = q0[512 + j];
    float g3r = q0[576 + j],     g3z = q0[640 + j],      g3n = q0[704 + j];

#pragma unroll 2
    for (int t = t0; t < eEnd; ++t) {
        const float* gq = gp + (size_t)(t + 4) * 192;   // benign over-read
        float g4r = gq[j], g4z = gq[64 + j], g4n = gq[128 + j];

        v2f ar0 = {0.f,0.f}, ar1 = {0.f,0.f};
        v2f az0 = {0.f,0.f}, az1 = {0.f,0.f};
        v2f an0 = {0.f,0.f}, an1 = {0.f,0.f};
        const float4* h4 = (const float4*)hsh;
#pragma unroll
        for (int k4 = 0; k4 < 16; ++k4) {
            float4 hv = h4[k4];
            v2f p0; p0.x = hv.x; p0.y = hv.y;
            v2f p1; p1.x = hv.z; p1.y = hv.w;
            ar0 = pkfma(wr[2*k4],   p0, ar0);
            ar1 = pkfma(wr[2*k4+1], p1, ar1);
            az0 = pkfma(wz[2*k4],   p0, az0);
            az1 = pkfma(wz[2*k4+1], p1, az1);
            an0 = pkfma(wn[2*k4],   p0, an0);
            an1 = pkfma(wn[2*k4+1], p1, an1);
        }
        float sr = ar0.x + ar0.y + ar1.x + ar1.y + br;
        float sz = az0.x + az0.y + az1.x + az1.y + bz;
        float sn = an0.x + an0.y + an1.x + an1.y + bn;
        float r  = sigmoidf_(g0r + sr);
        float z  = sigmoidf_(g0z + sz);
        float nn = tanhf_(fmaf(r, sn, g0n));
        hj = fmaf(z, hj - nn, nn);           // (1-z)*n + z*h
        hsh[j] = hj;                         // single wave: program-order vs reads

        if (t >= eStart) hp[(size_t)t * 64] = hj;   // emit range only

        g0r = g1r; g0z = g1z; g0n = g1n;
        g1r = g2r; g1z = g2z; g1n = g2n;
        g2r = g3r; g2z = g3z; g2n = g3n;
        g3r = g4r; g3z = g4z; g3n = g4n;
    }
}

// ---------------- K3: fused out-proj + fast path --------------------------
// r3-proven structure; this round vectorizes the three hot staging/epilogue
// loops (xs fast-path float4, hsl float4, phase-C float4 stores). outws
// staging kept scalar: its 65-stride layout is conflict-free but 16B-align-
// incompatible with float4 stores.
#define SROWS 24
__global__ __launch_bounds__(256) void k3_fast(const float* __restrict__ x,
                                               const float* __restrict__ fc1w,
                                               const float* __restrict__ fc1b,
                                               const float* __restrict__ fc2w,
                                               const float* __restrict__ fc2b,
                                               const float* __restrict__ outw,
                                               const float* __restrict__ outb,
                                               const float* __restrict__ hs,
                                               float* __restrict__ out) {
    int b  = blockIdx.y;
    int m0 = blockIdx.x * 64;
    int tid = threadIdx.x;

    __shared__ __align__(16) float gbs[SROWS * 64];   // 1536 floats (persistent)
    __shared__ __align__(16) float scr[5696];         // union scratch (22.8 KB)

    int fbase = m0 - 1;
    int s0 = (m0 - 1) / 3 - 1; if (s0 < 0) s0 = 0;

    // ---- phase P: eps rows [s0, s0+SROWS) ----
    {
        float* hsl   = scr;            // [SROWS][64]
        float* outws = scr + 1536;     // [64][65]  (+1 pad kills 64-stride conflicts)
        const float* hsb = hs + (size_t)b * NS * 64;
        for (int vi = tid; vi < SROWS * 16; vi += 256) {     // 384 float4
            int si = vi >> 4, k4 = vi & 15;
            int t = s0 + si;
            float4 v = {0.f, 0.f, 0.f, 0.f};
            if (t < NS) v = *(const float4*)(hsb + (size_t)t * 64 + k4 * 4);
            ((float4*)hsl)[vi] = v;
        }
        for (int i = tid; i < 64 * 64; i += 256) {
            int o = i >> 6, k = i & 63;
            outws[o * 65 + k] = outw[i];
        }
        __syncthreads();
        int o = tid & 63, q = tid >> 6;       // q = wave id (uniform per wave)
        float bias = outb[o];
        for (int si = q; si < SROWS; si += 4) {
            const float* hrow = hsl + si * 64;     // wave-uniform -> broadcast
            const float* wrow = outws + o * 65;    // stride-65 -> conflict-free
            v2f a0 = {0.f,0.f}, a1 = {0.f,0.f};
#pragma unroll
            for (int k = 0; k < 16; ++k) {
                v2f p0; p0.x = hrow[4*k];   p0.y = hrow[4*k+1];
                v2f p1; p1.x = hrow[4*k+2]; p1.y = hrow[4*k+3];
                v2f w0; w0.x = wrow[4*k];   w0.y = wrow[4*k+1];
                v2f w1_; w1_.x = wrow[4*k+2]; w1_.y = wrow[4*k+3];
                a0 = pkfma(w0,  p0, a0);
                a1 = pkfma(w1_, p1, a1);
            }
            gbs[si * 64 + o] = a0.x + a0.y + a1.x + a1.y + bias;
        }
        __syncthreads();   // gbs done; scr free for reuse
    }

    // ---- phase F ----
    float* xs  = scr;                  // 1056
    float* h1s = scr + 1056;           // 2080
    float* ys  = scr + 3136;           // 2080

    long xstart = (long)fbase * HOP;
    const float* xb = x + (size_t)b * TT;
    bool xfast = (fbase >= 0) && (xstart + 1056 <= TT);   // all but bx=0, bx=63
    if (xfast) {
        const float4* xsrc = (const float4*)(xb + xstart);  // 16B-aligned
        for (int vi = tid; vi < 264; vi += 256)
            ((float4*)xs)[vi] = xsrc[vi];
    } else {
        for (int i = tid; i < 1056; i += 256) {
            long p = xstart + i;
            xs[i] = (p >= 0 && p < TT) ? xb[p] : 0.f;
        }
    }

    int j  = tid & 31;
    int fi = tid >> 5;
    v2f w1[16], w2[16];
    {
        const v2f* r1 = (const v2f*)(fc1w + (size_t)j * 32);
        const v2f* r2 = (const v2f*)(fc2w + (size_t)j * 32);
#pragma unroll
        for (int k = 0; k < 16; ++k) { w1[k] = r1[k]; w2[k] = r2[k]; }
    }
    float b1 = fc1b[j];
    float b2 = fc2b[j];
    __syncthreads();

    // phase A: h1 = relu(g*fc1 + b)
    for (int ff = fi; ff < 65; ff += 8) {
        int f = fbase + ff;
        float v = 0.f;
        if (f >= 0 && f < NF) {
            const float4* xf4 = (const float4*)(xs + ff * HOP);
            v2f a0 = {0.f,0.f}, a1 = {0.f,0.f};
#pragma unroll
            for (int k4 = 0; k4 < 8; ++k4) {
                float4 xv = xf4[k4];
                v2f p0; p0.x = xv.x; p0.y = xv.y;
                v2f p1; p1.x = xv.z; p1.y = xv.w;
                a0 = pkfma(w1[2*k4],   p0, a0);
                a1 = pkfma(w1[2*k4+1], p1, a1);
            }
            float acc = a0.x + a0.y + a1.x + a1.y + b1;
            int sidx = f / DELTA - 1; if (sidx < 0) sidx = 0;
            const float* gp = gbs + (sidx - s0) * 64;
            v = fmaxf(fmaf(gp[j], acc, gp[32 + j]), 0.f);
        }
        h1s[ff * 32 + j] = v;
    }
    __syncthreads();

    // phase B: y = h1 @ fc2^T + fc2_b
    for (int ff = fi; ff < 65; ff += 8) {
        int f = fbase + ff;
        float v = 0.f;
        if (f >= 0 && f < NF) {
            const float4* hf4 = (const float4*)(h1s + ff * 32);
            v2f a0 = {0.f,0.f}, a1 = {0.f,0.f};
#pragma unroll
            for (int k4 = 0; k4 < 8; ++k4) {
                float4 hv = hf4[k4];
                v2f p0; p0.x = hv.x; p0.y = hv.y;
                v2f p1; p1.x = hv.z; p1.y = hv.w;
                a0 = pkfma(w2[2*k4],   p0, a0);
                a1 = pkfma(w2[2*k4+1], p1, a1);
            }
            v = a0.x + a0.y + a1.x + a1.y + b2;
        }
        ys[ff * 32 + j] = v;
    }
    __syncthreads();

    // phase C: overlap-add -> out (fp32), float4 stores (one vec per thread)
    {
        float4* ob4 = (float4*)(out + (size_t)b * TT + (size_t)m0 * HOP);
        for (int vi = tid; vi < 256; vi += 256) {
            int ml = vi >> 2, q4 = vi & 3;
            const float* ya = ys + (ml + 1) * 32 + q4 * 4;
            const float* yb = ys + ml * 32 + 16 + q4 * 4;
            float4 r;
            r.x = ya[0] + yb[0];
            r.y = ya[1] + yb[1];
            r.z = ya[2] + yb[2];
            r.w = ya[3] + yb[3];
            ob4[vi] = r;
        }
    }
}

// ---------------- launcher ----------------
extern "C" void kernel_launch(void* const* d_in, const int* in_sizes, int n_in,
                              void* d_out, int out_size, void* d_ws, size_t ws_size,
                              hipStream_t stream) {
    const float* x     = (const float*)d_in[0];
    const float* fc1w  = (const float*)d_in[1];
    const float* fc1b  = (const float*)d_in[2];
    const float* fc2w  = (const float*)d_in[3];
    const float* fc2b  = (const float*)d_in[4];
    const float* wih   = (const float*)d_in[5];
    const float* whh   = (const float*)d_in[6];
    const float* bih   = (const float*)d_in[7];
    const float* bhh   = (const float*)d_in[8];
    const float* outw  = (const float*)d_in[9];
    const float* outb  = (const float*)d_in[10];

    float* ws  = (float*)d_ws;
    float* gi  = ws + GI_BASE;
    float* hs  = ws + HS_BASE;
    float* out = (float*)d_out;

    k1_gi<<<K1NBLK, 384, 0, stream>>>(x, wih, bih, gi);

    k2_scan<<<dim3(NCHUNK, BB), 64, 0, stream>>>(whh, bhh, gi, hs);

    k3_fast<<<dim3((NF + 1) / 64, BB), 256, 0, stream>>>(x, fc1w, fc1b, fc2w, fc2b,
                                                         outw, outb, hs, out);
}

// Round 7
// 429.421 us; speedup vs baseline: 1.3276x; 1.0461x over previous
//
#include <hip/hip_runtime.h>
#include <hip/hip_bf16.h>

// ---------------- problem constants ----------------
#define BB    128
#define TT    65536
#define LF    32
#define HOP   16
#define DELTA 3
#define HID   32
#define GRUH  64
#define SWIN  96          // DELTA*HOP*2
#define SHOP  48          // DELTA*HOP
#define NF    4095        // (TT-LF)/HOP + 1
#define NS    1364        // (TT-SWIN)/SHOP + 1

// ---- chunked-scan parameters ----
// K2O=32 (r2-proven): ~2e-10 attenuation of unknown init state.
// K2C=86: 16 chunks x 128 b = 2048 waves = EXACTLY 8/CU balanced.
// LDS-throughput model (r6 post-mortem): per-CU per-step cost =
// waves/CU x 16 ds_read_b128 x ~12cyc. Total k2 LDS work scales with
// NS*(1+K2O/K2C) -> larger K2C wins on BOTH total work and per-step
// pipe pressure. Predicted 8*16*12=1536 cyc/step * 118 steps ~ 75us.
#define K2C    86
#define K2O    32
#define NCHUNK ((NS + K2C - 1) / K2C)   // 16

// ---------------- ws layout (float indices), total 178.8 MB (proven safe) ----
#define GI_BASE   0ull
#define HS_BASE   (GI_BASE + (unsigned long long)BB*NS*192)

typedef float v2f __attribute__((ext_vector_type(2)));

__device__ __forceinline__ float sigmoidf_(float x) {
    return __builtin_amdgcn_rcpf(1.f + __builtin_amdgcn_exp2f(-1.44269504f * x));
}
__device__ __forceinline__ float tanhf_(float x) {
    return 1.f - 2.f * __builtin_amdgcn_rcpf(1.f + __builtin_amdgcn_exp2f(2.88539008f * x));
}
__device__ __forceinline__ v2f pkfma(v2f a, v2f b, v2f c) {
    return __builtin_elementwise_fma(a, b, c);
}

// ---------------- K1: gi[b][n][j] = b_ih[j] + slow_frame(b,n) . w_ih[j,:] ----
// r3-proven structure (157us, restored r6). This round: SCALAR inner FMAs.
// r6 VALU arithmetic showed ~78 VALU insts/segment vs 24 pkfma + ~15 overhead
// expected -> compiler builds v2f operands from scalarized x (SGPRs) with
// v_mov pairs. Scalar fmaf reads the SGPR x directly (1 scalar operand/inst
// is legal): 48 v_fma + overhead ~ 63 insts/segment. Accumulation order kept
// bit-identical: acc0..acc3 = old a0.x,a0.y,a1.x,a1.y; cur=((acc0+acc1)+acc2)+acc3.
// Split-K by 2 unchanged: 384 thr/block, thread=(row,half), 48 weight floats
// per thread; frame n = segs {n,n+1}; pair combines via shfl_xor(1).
#define K1G    16
#define K1NG   ((NS + K1G - 1) / K1G)   // 86 groups
#define K1NBLK 2752
__global__ __launch_bounds__(384, 1) void k1_gi(const float* __restrict__ x,
                                                const float* __restrict__ wih,
                                                const float* __restrict__ bih,
                                                float* __restrict__ gi) {
    int tid  = threadIdx.x;
    int row  = tid >> 1;       // 0..191 = output row
    int half = tid & 1;        // 0: frame cols 0..47, 1: frame cols 48..95

    float w[48];
    const float* wr = wih + (size_t)row * 96 + half * 48;
#pragma unroll
    for (int k = 0; k < 48; ++k) w[k] = wr[k];
    float bias = bih[row];

    const int nwi = K1NG * BB;             // 11008 work items
#pragma unroll 1
    for (int wi = blockIdx.x; wi < nwi; wi += K1NBLK) {
#pragma unroll
        for (int k = 0; k < 48; ++k) asm volatile("" : "+v"(w[k]));  // no remat
        int b  = wi & (BB - 1);
        int n0 = (wi >> 7) * K1G;
        const float4* xb = (const float4*)(x + (size_t)b * TT);
        float* gout = gi + ((size_t)b * NS + n0) * 192 + row;

        float prev = 0.f;                  // half's partial for frame n0+s-1
#pragma unroll 1
        for (int s = 0; s <= K1G; ++s) {
            int seg = n0 + s; if (seg > NS) seg = NS;    // clamp: loads in-bounds
            const float4* xp = xb + (size_t)seg * 12;
            float4 xs[12];
#pragma unroll
            for (int k = 0; k < 12; ++k) xs[k] = xp[k];

            float acc0 = 0.f, acc1 = 0.f, acc2 = 0.f, acc3 = 0.f;
#pragma unroll
            for (int k = 0; k < 12; ++k) {
                acc0 = fmaf(xs[k].x, w[4*k + 0], acc0);
                acc1 = fmaf(xs[k].y, w[4*k + 1], acc1);
                acc2 = fmaf(xs[k].z, w[4*k + 2], acc2);
                acc3 = fmaf(xs[k].w, w[4*k + 3], acc3);
            }
            float cur = ((acc0 + acc1) + acc2) + acc3;

            if (s > 0) {
                // frame f = n0+s-1: half0 contributed at iter s-1, half1 now.
                float mine  = half ? cur : prev;
                float other = __shfl_xor(mine, 1, 64);
                int f = n0 + s - 1;
                if (half == 0 && f < NS)
                    gout[(size_t)(s - 1) * 192] = mine + other + bias;
            }
            prev = cur;
        }
    }
}

// ---------------- K2: chunked GRU scan (K2C=86, 4-deep gi prefetch) ---------
// blockIdx.x = chunk, blockIdx.y = batch; 1 wave each. Lane j owns W_hh rows
// {j,64+j,128+j} in regs; h broadcast via tiny LDS (single wave, no barriers).
__global__ __launch_bounds__(64) void k2_scan(const float* __restrict__ whh,
                                              const float* __restrict__ bhh,
                                              const float* __restrict__ gi,
                                              float* __restrict__ hs) {
    int c = blockIdx.x;
    int b = blockIdx.y;
    int j = threadIdx.x;
    __shared__ __align__(16) float hsh[GRUH];

    int eStart = c * K2C;
    int eEnd   = eStart + K2C; if (eEnd > NS) eEnd = NS;
    int t0     = eStart - K2O; if (t0 < 0) t0 = 0;

    v2f wr[32], wz[32], wn[32];
    const v2f* rr = (const v2f*)(whh + (size_t)j * 64);
    const v2f* rz = (const v2f*)(whh + (size_t)(64 + j) * 64);
    const v2f* rn = (const v2f*)(whh + (size_t)(128 + j) * 64);
#pragma unroll
    for (int k = 0; k < 32; ++k) { wr[k] = rr[k]; wz[k] = rz[k]; wn[k] = rn[k]; }
    float br = bhh[j], bz = bhh[64 + j], bn = bhh[128 + j];

    hsh[j] = 0.f;
    float hj = 0.f;
    const float* gp = gi + (size_t)b * NS * 192;
    float* hp = hs + (size_t)b * NS * 64 + j;

    // 4-deep shift prefetch (over-reads land in hs region: allocated, benign)
    const float* q0 = gp + (size_t)t0 * 192;
    float g0r = q0[j],           g0z = q0[64 + j],       g0n = q0[128 + j];
    float g1r = q0[192 + j],     g1z = q0[256 + j],      g1n = q0[320 + j];
    float g2r = q0[384 + j],     g2z = q0[448 + j],      g2n = q0[512 + j];
    float g3r = q0[576 + j],     g3z = q0[640 + j],      g3n = q0[704 + j];

#pragma unroll 2
    for (int t = t0; t < eEnd; ++t) {
        const float* gq = gp + (size_t)(t + 4) * 192;   // benign over-read
        float g4r = gq[j], g4z = gq[64 + j], g4n = gq[128 + j];

        v2f ar0 = {0.f,0.f}, ar1 = {0.f,0.f};
        v2f az0 = {0.f,0.f}, az1 = {0.f,0.f};
        v2f an0 = {0.f,0.f}, an1 = {0.f,0.f};
        const float4* h4 = (const float4*)hsh;
#pragma unroll
        for (int k4 = 0; k4 < 16; ++k4) {
            float4 hv = h4[k4];
            v2f p0; p0.x = hv.x; p0.y = hv.y;
            v2f p1; p1.x = hv.z; p1.y = hv.w;
            ar0 = pkfma(wr[2*k4],   p0, ar0);
            ar1 = pkfma(wr[2*k4+1], p1, ar1);
            az0 = pkfma(wz[2*k4],   p0, az0);
            az1 = pkfma(wz[2*k4+1], p1, az1);
            an0 = pkfma(wn[2*k4],   p0, an0);
            an1 = pkfma(wn[2*k4+1], p1, an1);
        }
        float sr = ar0.x + ar0.y + ar1.x + ar1.y + br;
        float sz = az0.x + az0.y + az1.x + az1.y + bz;
        float sn = an0.x + an0.y + an1.x + an1.y + bn;
        float r  = sigmoidf_(g0r + sr);
        float z  = sigmoidf_(g0z + sz);
        float nn = tanhf_(fmaf(r, sn, g0n));
        hj = fmaf(z, hj - nn, nn);           // (1-z)*n + z*h
        hsh[j] = hj;                         // single wave: program-order vs reads

        if (t >= eStart) hp[(size_t)t * 64] = hj;   // emit range only

        g0r = g1r; g0z = g1z; g0n = g1n;
        g1r = g2r; g1z = g2z; g1n = g2n;
        g2r = g3r; g2z = g3z; g2n = g3n;
        g3r = g4r; g3z = g4z; g3n = g4n;
    }
}

// ---------------- K3: fused out-proj + fast path (r6 version, unchanged) ---
#define SROWS 24
__global__ __launch_bounds__(256) void k3_fast(const float* __restrict__ x,
                                               const float* __restrict__ fc1w,
                                               const float* __restrict__ fc1b,
                                               const float* __restrict__ fc2w,
                                               const float* __restrict__ fc2b,
                                               const float* __restrict__ outw,
                                               const float* __restrict__ outb,
                                               const float* __restrict__ hs,
                                               float* __restrict__ out) {
    int b  = blockIdx.y;
    int m0 = blockIdx.x * 64;
    int tid = threadIdx.x;

    __shared__ __align__(16) float gbs[SROWS * 64];   // 1536 floats (persistent)
    __shared__ __align__(16) float scr[5696];         // union scratch (22.8 KB)

    int fbase = m0 - 1;
    int s0 = (m0 - 1) / 3 - 1; if (s0 < 0) s0 = 0;

    // ---- phase P: eps rows [s0, s0+SROWS) ----
    {
        float* hsl   = scr;            // [SROWS][64]
        float* outws = scr + 1536;     // [64][65]  (+1 pad kills 64-stride conflicts)
        const float* hsb = hs + (size_t)b * NS * 64;
        for (int vi = tid; vi < SROWS * 16; vi += 256) {     // 384 float4
            int si = vi >> 4, k4 = vi & 15;
            int t = s0 + si;
            float4 v = {0.f, 0.f, 0.f, 0.f};
            if (t < NS) v = *(const float4*)(hsb + (size_t)t * 64 + k4 * 4);
            ((float4*)hsl)[vi] = v;
        }
        for (int i = tid; i < 64 * 64; i += 256) {
            int o = i >> 6, k = i & 63;
            outws[o * 65 + k] = outw[i];
        }
        __syncthreads();
        int o = tid & 63, q = tid >> 6;       // q = wave id (uniform per wave)
        float bias = outb[o];
        for (int si = q; si < SROWS; si += 4) {
            const float* hrow = hsl + si * 64;     // wave-uniform -> broadcast
            const float* wrow = outws + o * 65;    // stride-65 -> conflict-free
            v2f a0 = {0.f,0.f}, a1 = {0.f,0.f};
#pragma unroll
            for (int k = 0; k < 16; ++k) {
                v2f p0; p0.x = hrow[4*k];   p0.y = hrow[4*k+1];
                v2f p1; p1.x = hrow[4*k+2]; p1.y = hrow[4*k+3];
                v2f w0; w0.x = wrow[4*k];   w0.y = wrow[4*k+1];
                v2f w1_; w1_.x = wrow[4*k+2]; w1_.y = wrow[4*k+3];
                a0 = pkfma(w0,  p0, a0);
                a1 = pkfma(w1_, p1, a1);
            }
            gbs[si * 64 + o] = a0.x + a0.y + a1.x + a1.y + bias;
        }
        __syncthreads();   // gbs done; scr free for reuse
    }

    // ---- phase F ----
    float* xs  = scr;                  // 1056
    float* h1s = scr + 1056;           // 2080
    float* ys  = scr + 3136;           // 2080

    long xstart = (long)fbase * HOP;
    const float* xb = x + (size_t)b * TT;
    bool xfast = (fbase >= 0) && (xstart + 1056 <= TT);   // all but bx=0, bx=63
    if (xfast) {
        const float4* xsrc = (const float4*)(xb + xstart);  // 16B-aligned
        for (int vi = tid; vi < 264; vi += 256)
            ((float4*)xs)[vi] = xsrc[vi];
    } else {
        for (int i = tid; i < 1056; i += 256) {
            long p = xstart + i;
            xs[i] = (p >= 0 && p < TT) ? xb[p] : 0.f;
        }
    }

    int j  = tid & 31;
    int fi = tid >> 5;
    v2f w1[16], w2[16];
    {
        const v2f* r1 = (const v2f*)(fc1w + (size_t)j * 32);
        const v2f* r2 = (const v2f*)(fc2w + (size_t)j * 32);
#pragma unroll
        for (int k = 0; k < 16; ++k) { w1[k] = r1[k]; w2[k] = r2[k]; }
    }
    float b1 = fc1b[j];
    float b2 = fc2b[j];
    __syncthreads();

    // phase A: h1 = relu(g*fc1 + b)
    for (int ff = fi; ff < 65; ff += 8) {
        int f = fbase + ff;
        float v = 0.f;
        if (f >= 0 && f < NF) {
            const float4* xf4 = (const float4*)(xs + ff * HOP);
            v2f a0 = {0.f,0.f}, a1 = {0.f,0.f};
#pragma unroll
            for (int k4 = 0; k4 < 8; ++k4) {
                float4 xv = xf4[k4];
                v2f p0; p0.x = xv.x; p0.y = xv.y;
                v2f p1; p1.x = xv.z; p1.y = xv.w;
                a0 = pkfma(w1[2*k4],   p0, a0);
                a1 = pkfma(w1[2*k4+1], p1, a1);
            }
            float acc = a0.x + a0.y + a1.x + a1.y + b1;
            int sidx = f / DELTA - 1; if (sidx < 0) sidx = 0;
            const float* gp = gbs + (sidx - s0) * 64;
            v = fmaxf(fmaf(gp[j], acc, gp[32 + j]), 0.f);
        }
        h1s[ff * 32 + j] = v;
    }
    __syncthreads();

    // phase B: y = h1 @ fc2^T + fc2_b
    for (int ff = fi; ff < 65; ff += 8) {
        int f = fbase + ff;
        float v = 0.f;
        if (f >= 0 && f < NF) {
            const float4* hf4 = (const float4*)(h1s + ff * 32);
            v2f a0 = {0.f,0.f}, a1 = {0.f,0.f};
#pragma unroll
            for (int k4 = 0; k4 < 8; ++k4) {
                float4 hv = hf4[k4];
                v2f p0; p0.x = hv.x; p0.y = hv.y;
                v2f p1; p1.x = hv.z; p1.y = hv.w;
                a0 = pkfma(w2[2*k4],   p0, a0);
                a1 = pkfma(w2[2*k4+1], p1, a1);
            }
            v = a0.x + a0.y + a1.x + a1.y + b2;
        }
        ys[ff * 32 + j] = v;
    }
    __syncthreads();

    // phase C: overlap-add -> out (fp32), float4 stores (one vec per thread)
    {
        float4* ob4 = (float4*)(out + (size_t)b * TT + (size_t)m0 * HOP);
        for (int vi = tid; vi < 256; vi += 256) {
            int ml = vi >> 2, q4 = vi & 3;
            const float* ya = ys + (ml + 1) * 32 + q4 * 4;
            const float* yb = ys + ml * 32 + 16 + q4 * 4;
            float4 r;
            r.x = ya[0] + yb[0];
            r.y = ya[1] + yb[1];
            r.z = ya[2] + yb[2];
            r.w = ya[3] + yb[3];
            ob4[vi] = r;
        }
    }
}

// ---------------- launcher ----------------
extern "C" void kernel_launch(void* const* d_in, const int* in_sizes, int n_in,
                              void* d_out, int out_size, void* d_ws, size_t ws_size,
                              hipStream_t stream) {
    const float* x     = (const float*)d_in[0];
    const float* fc1w  = (const float*)d_in[1];
    const float* fc1b  = (const float*)d_in[2];
    const float* fc2w  = (const float*)d_in[3];
    const float* fc2b  = (const float*)d_in[4];
    const float* wih   = (const float*)d_in[5];
    const float* whh   = (const float*)d_in[6];
    const float* bih   = (const float*)d_in[7];
    const float* bhh   = (const float*)d_in[8];
    const float* outw  = (const float*)d_in[9];
    const float* outb  = (const float*)d_in[10];

    float* ws  = (float*)d_ws;
    float* gi  = ws + GI_BASE;
    float* hs  = ws + HS_BASE;
    float* out = (float*)d_out;

    k1_gi<<<K1NBLK, 384, 0, stream>>>(x, wih, bih, gi);

    k2_scan<<<dim3(NCHUNK, BB), 64, 0, stream>>>(whh, bhh, gi, hs);

    k3_fast<<<dim3((NF + 1) / 64, BB), 256, 0, stream>>>(x, fc1w, fc1b, fc2w, fc2b,
                                                         outw, outb, hs, out);
}